// Round 5
// baseline (172.162 us; speedup 1.0000x reference)
//
#include <hip/hip_runtime.h>

#define BB 32
#define MM 512
#define SS 10
#define VV 32000
#define DD 128
#define HOPS 3
#define BM (BB * MM)

#define NP 500          // v-chunks (64 rows each) for gemv/gemm grids
#define VPB 64          // vocab rows per block

// ====================== PRIMARY PATH (histogram / dual-GEMV, GEMM-structured) ======================

// K1: cu[v][b] = dot(A[v,:], uin[b,:]).  One wave per block; tile 64v x 32b.
// Also zeroes this chunk's hist rows; block 0 zeroes den.
// LDS layout: column-quads XOR-swizzled so compute reads are bank-conflict-free.
__global__ __launch_bounds__(64) void gemv_cu(const float* __restrict__ A,
                                              const float* __restrict__ uin,
                                              float* __restrict__ cu,
                                              float* __restrict__ hist,
                                              float* __restrict__ den) {
    __shared__ float As[VPB * DD];   // quad-swizzled: col4 ^ ((v>>3)&7)
    __shared__ float ss[BB * DD];    // quad-swizzled: col4 ^ ((b>>2)&7)
    const int t = threadIdx.x;
    const int v0 = blockIdx.x * VPB;

    // stage A tile: 64 rows x 512B, fully coalesced
    const float4* Ag = (const float4*)(A + (size_t)v0 * DD);
#pragma unroll
    for (int i = 0; i < 32; ++i) {
        const int f4 = i * 64 + t;               // 0..2047
        const float4 val = Ag[f4];
        const int v = f4 >> 5, d4 = f4 & 31;
        ((float4*)As)[(v << 5) | (d4 ^ ((v >> 3) & 7))] = val;
    }
    // stage u: 32 x 128
    const float4* ug = (const float4*)uin;
#pragma unroll
    for (int i = 0; i < 16; ++i) {
        const int f4 = i * 64 + t;               // 0..1023
        const float4 val = ug[f4];
        const int b = f4 >> 5, d4 = f4 & 31;
        ((float4*)ss)[(b << 5) | (d4 ^ ((b >> 2) & 7))] = val;
    }
    // zero hist chunk (64*32 floats = 512 float4)
    const float4 z = make_float4(0.f, 0.f, 0.f, 0.f);
    float4* hz = (float4*)(hist + (size_t)v0 * BB);
#pragma unroll
    for (int i = 0; i < 8; ++i) hz[i * 64 + t] = z;
    if (blockIdx.x == 0 && t < BB) den[t] = 0.f;
    __syncthreads();

    const int vg = t >> 3;   // [0,8): 8 rows each
    const int bg = t & 7;    // [0,8): 4 b each
    float acc[8][4];
#pragma unroll
    for (int i = 0; i < 8; ++i)
#pragma unroll
        for (int j = 0; j < 4; ++j) acc[i][j] = 0.f;

    for (int d4 = 0; d4 < 32; ++d4) {
        float4 s[4];
#pragma unroll
        for (int j = 0; j < 4; ++j)
            s[j] = ((const float4*)ss)[((bg * 4 + j) << 5) | (d4 ^ bg)];
#pragma unroll
        for (int i = 0; i < 8; ++i) {
            const float4 a = ((const float4*)As)[((vg * 8 + i) << 5) | (d4 ^ vg)];
#pragma unroll
            for (int j = 0; j < 4; ++j)
                acc[i][j] += a.x * s[j].x + a.y * s[j].y + a.z * s[j].z + a.w * s[j].w;
        }
    }
#pragma unroll
    for (int i = 0; i < 8; ++i)
        *(float4*)(cu + (size_t)(v0 + vg * 8 + i) * BB + bg * 4) =
            make_float4(acc[i][0], acc[i][1], acc[i][2], acc[i][3]);
}

// K2: per (b,m): l = sum_s cu[tok][b]; e = exp(l) (max-free); scatter into hist,den.
template <int WRITE_LOGIT>
__global__ __launch_bounds__(128) void scatter_w(const int* __restrict__ story,
                                                 const float* __restrict__ cu,
                                                 float* __restrict__ hist,
                                                 float* __restrict__ den,
                                                 float* __restrict__ logit) {
    const int bm = blockIdx.x * 128 + threadIdx.x;
    const int b = bm >> 9;
    const int* st = story + (size_t)bm * SS;
    int tok[SS];
#pragma unroll
    for (int s = 0; s < SS; ++s) tok[s] = st[s];
    float l = 0.f;
#pragma unroll
    for (int s = 0; s < SS; ++s) l += cu[(size_t)tok[s] * BB + b];
    if (WRITE_LOGIT) logit[bm] = l;
    const float e = expf(l);
#pragma unroll
    for (int s = 0; s < SS; ++s) unsafeAtomicAdd(&hist[(size_t)tok[s] * BB + b], e);
    float sv = e;
#pragma unroll
    for (int off = 32; off; off >>= 1) sv += __shfl_xor(sv, off, 64);
    if ((threadIdx.x & 63) == 0) unsafeAtomicAdd(&den[b], sv);
}

// K3: P[blk][b][d] = sum_{v in chunk} hist[v][b] * Cn[v][d].  One wave per block.
// Thread (bg,dg): 4 b x 16 d, d-quads interleaved {dg, dg+8, dg+16, dg+24} -> conflict-free b128.
__global__ __launch_bounds__(64) void hist_gemm(const float* __restrict__ Cn,
                                                const float* __restrict__ hist,
                                                float* __restrict__ P) {
    __shared__ float Cs[VPB * DD];   // linear
    __shared__ float hs[VPB * BB];   // linear
    const int t = threadIdx.x;
    const int v0 = blockIdx.x * VPB;
    const float4* Cg = (const float4*)(Cn + (size_t)v0 * DD);
#pragma unroll
    for (int i = 0; i < 32; ++i) ((float4*)Cs)[i * 64 + t] = Cg[i * 64 + t];
    const float4* hg = (const float4*)(hist + (size_t)v0 * BB);
#pragma unroll
    for (int i = 0; i < 8; ++i) ((float4*)hs)[i * 64 + t] = hg[i * 64 + t];
    __syncthreads();

    const int bg = t >> 3;   // [0,8): 4 b each
    const int dg = t & 7;    // [0,8): quads {dg+8k}
    float4 acc[4][4];
#pragma unroll
    for (int j = 0; j < 4; ++j)
#pragma unroll
        for (int k = 0; k < 4; ++k) acc[j][k] = make_float4(0.f, 0.f, 0.f, 0.f);

    for (int v = 0; v < VPB; ++v) {
        float h[4];
#pragma unroll
        for (int j = 0; j < 4; ++j) h[j] = hs[v * BB + bg * 4 + j];
#pragma unroll
        for (int k = 0; k < 4; ++k) {
            const float4 c = ((const float4*)(Cs + v * DD))[dg + 8 * k];
#pragma unroll
            for (int j = 0; j < 4; ++j) {
                acc[j][k].x += h[j] * c.x;
                acc[j][k].y += h[j] * c.y;
                acc[j][k].z += h[j] * c.z;
                acc[j][k].w += h[j] * c.w;
            }
        }
    }
    float* Pb = P + (size_t)blockIdx.x * (BB * DD);
#pragma unroll
    for (int j = 0; j < 4; ++j)
#pragma unroll
        for (int k = 0; k < 4; ++k)
            ((float4*)(Pb + (size_t)(bg * 4 + j) * DD))[dg + 8 * k] = acc[j][k];
}

// K4: uout[b][d] = ubase[b][d] + (sum_p P[p][b][d]) / den[b].  grid 128 = (b, d-quarter).
__global__ __launch_bounds__(256) void reduce_P(const float* __restrict__ P,
                                                const float* __restrict__ ubase,
                                                const float* __restrict__ den,
                                                float* __restrict__ uout) {
    const int b = blockIdx.x >> 2, dq = blockIdx.x & 3;
    const int d = dq * 32 + (threadIdx.x & 31);
    const int pg = threadIdx.x >> 5;
    float s = 0.f;
    for (int p = pg; p < NP; p += 8) s += P[(size_t)p * (BB * DD) + b * DD + d];
    __shared__ float red[256];
    red[threadIdx.x] = s;
    __syncthreads();
    if (pg == 0) {
        float tot = 0.f;
#pragma unroll
        for (int g = 0; g < 8; ++g) tot += red[g * 32 + (threadIdx.x & 31)];
        uout[b * DD + d] = ubase[b * DD + d] + tot / den[b];
    }
}

// ====================== FALLBACK PATH (round-1, known-good) ======================
__global__ __launch_bounds__(256) void init_u(const float* __restrict__ hidden,
                                              float* __restrict__ u) {
    int i = blockIdx.x * 256 + threadIdx.x;
    if (i < BB * DD) u[i] = hidden[i];
}

__global__ __launch_bounds__(256) void logit_kernel(const int* __restrict__ story,
                                                    const float* __restrict__ Ch,
                                                    const float* __restrict__ u,
                                                    float* __restrict__ logit) {
    int wid = (blockIdx.x * 256 + threadIdx.x) >> 6;
    int lane = threadIdx.x & 63;
    if (wid >= BB * MM) return;
    int b = wid >> 9;
    const int* st = story + (size_t)wid * SS;
    int tok[SS];
#pragma unroll
    for (int s = 0; s < SS; ++s) tok[s] = st[s];
    float ax = 0.f, ay = 0.f;
#pragma unroll
    for (int s = 0; s < SS; ++s) {
        const float2 v = ((const float2*)(Ch + (size_t)tok[s] * DD))[lane];
        ax += v.x; ay += v.y;
    }
    const float2 uv = ((const float2*)(u + b * DD))[lane];
    float p = ax * uv.x + ay * uv.y;
#pragma unroll
    for (int off = 32; off; off >>= 1) p += __shfl_down(p, off, 64);
    if (lane == 0) logit[wid] = p;
}

__global__ __launch_bounds__(256) void softmax_kernel(const float* __restrict__ logit,
                                                      float* __restrict__ prob) {
    int b = blockIdx.x;
    int t = threadIdx.x;
    __shared__ float red[8];
    float l0 = logit[b * MM + t];
    float l1 = logit[b * MM + 256 + t];
    float mx = fmaxf(l0, l1);
#pragma unroll
    for (int off = 32; off; off >>= 1) mx = fmaxf(mx, __shfl_xor(mx, off, 64));
    if ((t & 63) == 0) red[t >> 6] = mx;
    __syncthreads();
    mx = fmaxf(fmaxf(red[0], red[1]), fmaxf(red[2], red[3]));
    float e0 = expf(l0 - mx), e1 = expf(l1 - mx);
    float s = e0 + e1;
#pragma unroll
    for (int off = 32; off; off >>= 1) s += __shfl_xor(s, off, 64);
    if ((t & 63) == 0) red[4 + (t >> 6)] = s;
    __syncthreads();
    s = red[4] + red[5] + red[6] + red[7];
    float inv = 1.0f / s;
    prob[b * MM + t] = e0 * inv;
    prob[b * MM + 256 + t] = e1 * inv;
}

__global__ __launch_bounds__(256) void partial_kernel(const int* __restrict__ story,
                                                      const float* __restrict__ Ch1,
                                                      const float* __restrict__ prob,
                                                      float* __restrict__ partial,
                                                      int chunk) {
    int b = blockIdx.y, c = blockIdx.x;
    int w = threadIdx.x >> 6, lane = threadIdx.x & 63;
    int m0 = c * chunk;
    float ax = 0.f, ay = 0.f;
    for (int m = m0 + w; m < m0 + chunk; m += 4) {
        float pw = prob[b * MM + m];
        const int* st = story + (size_t)(b * MM + m) * SS;
        int tok[SS];
#pragma unroll
        for (int s = 0; s < SS; ++s) tok[s] = st[s];
        float sx = 0.f, sy = 0.f;
#pragma unroll
        for (int s = 0; s < SS; ++s) {
            const float2 v = ((const float2*)(Ch1 + (size_t)tok[s] * DD))[lane];
            sx += v.x; sy += v.y;
        }
        ax += pw * sx; ay += pw * sy;
    }
    __shared__ float redx[4][64];
    __shared__ float redy[4][64];
    redx[w][lane] = ax;
    redy[w][lane] = ay;
    __syncthreads();
    if (w == 0) {
        float ox = redx[0][lane] + redx[1][lane] + redx[2][lane] + redx[3][lane];
        float oy = redy[0][lane] + redy[1][lane] + redy[2][lane] + redy[3][lane];
        float2* dst = (float2*)(partial + ((size_t)b * gridDim.x + c) * DD);
        dst[lane] = make_float2(ox, oy);
    }
}

__global__ __launch_bounds__(256) void update_kernel(const float* __restrict__ partial,
                                                     float* __restrict__ u, int NC) {
    int i = blockIdx.x * 256 + threadIdx.x;
    if (i >= BB * DD) return;
    int b = i >> 7, d = i & 127;
    float s = 0.f;
    for (int c = 0; c < NC; ++c) s += partial[((size_t)b * NC + c) * DD + d];
    u[i] += s;
}

extern "C" void kernel_launch(void* const* d_in, const int* in_sizes, int n_in,
                              void* d_out, int out_size, void* d_ws, size_t ws_size,
                              hipStream_t stream) {
    const int*   story  = (const int*)d_in[0];
    const float* hidden = (const float*)d_in[1];
    const float* Cmat   = (const float*)d_in[2];

    float* out   = (float*)d_out;
    float* logit = out;              // final prob_logit [B,M]
    float* uout  = out + BB * MM;    // final u [B,D]

    // ws floats: cu | hist | P | den | u1 | u2
    const size_t szCU = (size_t)VV * BB;          // 1.024M
    const size_t szP  = (size_t)NP * BB * DD;     // 2.048M
    const size_t need = (2 * szCU + szP + 32 + 2 * BB * DD) * sizeof(float);

    if (ws_size >= need) {
        float* cu   = (float*)d_ws;
        float* hist = cu + szCU;
        float* P    = hist + szCU;
        float* den  = P + szP;
        float* u1   = den + 32;
        float* u2   = u1 + BB * DD;

        const float* C0 = Cmat;
        const float* C1 = Cmat + (size_t)1 * VV * DD;
        const float* C2 = Cmat + (size_t)2 * VV * DD;
        const float* C3 = Cmat + (size_t)3 * VV * DD;

        // hop 0
        gemv_cu<<<NP, 64, 0, stream>>>(C0, hidden, cu, hist, den);
        scatter_w<0><<<BM / 128, 128, 0, stream>>>(story, cu, hist, den, nullptr);
        hist_gemm<<<NP, 64, 0, stream>>>(C1, hist, P);
        reduce_P<<<128, 256, 0, stream>>>(P, hidden, den, u1);
        // hop 1
        gemv_cu<<<NP, 64, 0, stream>>>(C1, u1, cu, hist, den);
        scatter_w<0><<<BM / 128, 128, 0, stream>>>(story, cu, hist, den, nullptr);
        hist_gemm<<<NP, 64, 0, stream>>>(C2, hist, P);
        reduce_P<<<128, 256, 0, stream>>>(P, u1, den, u2);
        // hop 2
        gemv_cu<<<NP, 64, 0, stream>>>(C2, u2, cu, hist, den);
        scatter_w<1><<<BM / 128, 128, 0, stream>>>(story, cu, hist, den, logit);
        hist_gemm<<<NP, 64, 0, stream>>>(C3, hist, P);
        reduce_P<<<128, 256, 0, stream>>>(P, u2, den, uout);
    } else {
        float* prob = (float*)d_ws;
        int NC = 32;
        while (NC > 1 && (size_t)(BB * MM + BB * NC * DD) * 4 > ws_size) NC >>= 1;
        float* partial = prob + BB * MM;
        int chunk = MM / NC;

        init_u<<<(BB * DD + 255) / 256, 256, 0, stream>>>(hidden, uout);
        for (int h = 0; h < HOPS; ++h) {
            const float* Ca = Cmat + (size_t)h * VV * DD;
            const float* Cc = Cmat + (size_t)(h + 1) * VV * DD;
            logit_kernel<<<(BB * MM) / 4, 256, 0, stream>>>(story, Ca, uout, logit);
            softmax_kernel<<<BB, 256, 0, stream>>>(logit, prob);
            partial_kernel<<<dim3(NC, BB), 256, 0, stream>>>(story, Cc, prob, partial, chunk);
            update_kernel<<<(BB * DD + 255) / 256, 256, 0, stream>>>(partial, uout, NC);
        }
    }
}